// Round 14
// baseline (1086.159 us; speedup 1.0000x reference)
//
#include <hip/hip_runtime.h>

#define N_NODES 30000
#define N_EDGES 200000
#define DIM 768
#define N_REL 10
#define N_LAYERS 2
#define LN_EPS 1e-5f
#define W_ELEMS (DIM * DIM)
#define BKS 64               // GEMM k-step
#define NT (DIM / BKS)       // 12 K-steps
#define GT2_MAX 792          // compact 256-row tiles upper bound: E/256 + N_REL
#define N_ROOT_TILES ((N_NODES + 255) / 256)  // 118
#define GT2_ALL (GT2_MAX + N_ROOT_TILES)      // 910

typedef _Float16 f16;
typedef _Float16 f16x4 __attribute__((ext_vector_type(4)));
typedef _Float16 f16x8 __attribute__((ext_vector_type(8)));
typedef float f32x4 __attribute__((ext_vector_type(4)));

#define GLD(gaddr, laddr)                                                              \
    __builtin_amdgcn_global_load_lds((const __attribute__((address_space(1))) void*)(gaddr), \
                                     (__attribute__((address_space(3))) void*)(laddr), 16, 0, 0)

// ---- count: cnt[dst][r], deg[dst]; mark (r,src) presence with plain store ----
__global__ void count_kernel(const int* __restrict__ ei, const int* __restrict__ et,
                             int* __restrict__ cnt, int* __restrict__ deg,
                             int* __restrict__ posmap) {
    int e = blockIdx.x * blockDim.x + threadIdx.x;
    if (e >= N_EDGES) return;
    int src = ei[e];
    int dst = ei[N_EDGES + e];
    int r = et[e];
    atomicAdd(&cnt[dst * N_REL + r], 1);
    atomicAdd(&deg[dst], 1);
    posmap[r * N_NODES + src] = 1;  // idempotent mark
}

// ---- per-relation position scan: flags -> dense positions (src-ordered), mr[r] ----
#define PSCAN_CHUNK 118  // 256*118 >= N_NODES
__global__ void posscan_kernel(int* __restrict__ posmap, int* __restrict__ mr) {
    __shared__ int part[256];
    const int r = blockIdx.x;
    int* pm = posmap + (size_t)r * N_NODES;
    const int t = threadIdx.x;
    const int c0 = t * PSCAN_CHUNK;
    int s = 0;
    for (int i = 0; i < PSCAN_CHUNK; ++i) {
        const int idx = c0 + i;
        if (idx < N_NODES && pm[idx] == 1) ++s;
    }
    part[t] = s;
    __syncthreads();
    if (t == 0) {
        int a = 0;
        for (int i = 0; i < 256; ++i) { const int v = part[i]; part[i] = a; a += v; }
        mr[r] = a;
    }
    __syncthreads();
    int a = part[t];
    for (int i = 0; i < PSCAN_CHUNK; ++i) {
        const int idx = c0 + i;
        if (idx < N_NODES && pm[idx] == 1) pm[idx] = a++;
    }
}

// ---- single-block scan: row_start = exclusive prefix of deg; cursor = copy ----
#define SCAN_CHUNK 118
__global__ void scan_kernel(const int* __restrict__ deg, int* __restrict__ row_start,
                            int* __restrict__ cursor) {
    __shared__ int part[256];
    __shared__ int off[257];
    const int t = threadIdx.x;
    const int c0 = t * SCAN_CHUNK;
    int s = 0;
    for (int i = 0; i < SCAN_CHUNK; ++i) {
        const int idx = c0 + i;
        if (idx < N_NODES) s += deg[idx];
    }
    part[t] = s;
    __syncthreads();
    if (t == 0) {
        int a = 0;
        for (int i = 0; i < 256; ++i) { off[i] = a; a += part[i]; }
        off[256] = a;
        row_start[N_NODES] = a;
    }
    __syncthreads();
    int a = off[t];
    for (int i = 0; i < SCAN_CHUNK; ++i) {
        const int idx = c0 + i;
        if (idx < N_NODES) {
            row_start[idx] = a;
            cursor[idx] = a;
            a += deg[idx];
        }
    }
}

// ---- zbase (256-aligned prefix of mr) + tile->rel table (+ root tiles) ----
__global__ void zprep_kernel(const int* __restrict__ mr, int* __restrict__ zbase,
                             int* __restrict__ tile_rel) {
    if (blockIdx.x == 0 && threadIdx.x == 0) {
        int zc = 0, tc = 0;
        for (int r = 0; r < N_REL; ++r) {
            zbase[r] = zc;
            const int nt = (mr[r] + 255) >> 8;
            for (int i = 0; i < nt; ++i) tile_rel[tc + i] = r;
            tc += nt;
            zc += nt << 8;
        }
        for (int i = 0; i < N_ROOT_TILES; ++i) tile_rel[tc + i] = N_REL + i;
    }
}

// ---- fill CSR: pack = (rel<<24) | zrow; srclist[zrow] = src ----
__global__ void fill_kernel(const int* __restrict__ ei, const int* __restrict__ et,
                            const int* __restrict__ posmap, const int* __restrict__ zbase,
                            int* __restrict__ cursor, int* __restrict__ pack,
                            int* __restrict__ srclist) {
    int e = blockIdx.x * blockDim.x + threadIdx.x;
    if (e >= N_EDGES) return;
    int src = ei[e];
    int dst = ei[N_EDGES + e];
    int r = et[e];
    const int zrow = zbase[r] + posmap[r * N_NODES + src];
    int pos = atomicAdd(&cursor[dst], 1);
    pack[pos] = (r << 24) | zrow;
    srclist[zrow] = src;  // idempotent
}

// ---- f32 -> f16 elementwise (x into hf16) ----
__global__ void convx_kernel(const float* __restrict__ in, f16* __restrict__ out) {
    int idx = blockIdx.x * blockDim.x + threadIdx.x;
    if (idx >= N_NODES * DIM / 4) return;
    const float4 v = *reinterpret_cast<const float4*>(in + (size_t)idx * 4);
    f16x4 o = {(f16)v.x, (f16)v.y, (f16)v.z, (f16)v.w};
    *reinterpret_cast<f16x4*>(out + (size_t)idx * 4) = o;
}

// ---- W convert + transpose: WT[s][j][k] = Wsrc[s][k][j] as f16 ----
__global__ void convw_kernel(const float* __restrict__ Wrel, const float* __restrict__ Wroot,
                             f16* __restrict__ WT, int layer) {
    __shared__ float tile[32][33];
    const int s = blockIdx.z;
    const float* src = (s < N_REL) ? (Wrel + ((size_t)layer * N_REL + s) * W_ELEMS)
                                   : (Wroot + (size_t)layer * W_ELEMS);
    const int k0 = blockIdx.x * 32;
    const int j0 = blockIdx.y * 32;
    const int tx = threadIdx.x;
    const int ty = threadIdx.y;
#pragma unroll
    for (int i = 0; i < 4; ++i)
        tile[ty + i * 8][tx] = src[(size_t)(k0 + ty + i * 8) * DIM + j0 + tx];
    __syncthreads();
    f16* dst = WT + (size_t)s * W_ELEMS;
#pragma unroll
    for (int i = 0; i < 4; ++i)
        dst[(size_t)(j0 + ty + i * 8) * DIM + k0 + tx] = (f16)tile[tx][ty + i * 8];
}

// ---- f16 MFMA GEMM: 256x256 tile, 8 waves (2Mx4N, per-wave 128x64), 2-phase ----
// tile_rel[gt]: <0 exit | [0,N_REL) compact (A via srclist, Z f16 out)
//             | >=N_REL root tile (dense rows, W_root slab, f32 agg out)
// LDS: [2 dbuf][2 half][128][64] per operand = 128 KB -> 1 block/CU, 8 waves.
// 16B k-chunks XOR-swizzled c^(row&7); linear GLD dest + pre-swizzled source.
__global__ void __launch_bounds__(512, 2)
gemm_kernel(const f16* __restrict__ A, const f16* __restrict__ WT,
            const int* __restrict__ srclist, const int* __restrict__ tile_rel,
            f16* __restrict__ Zout, float* __restrict__ aggout) {
    __shared__ alignas(128) f16 As[2][2][128 * BKS];  // 64 KB
    __shared__ alignas(128) f16 Bs[2][2][128 * BKS];  // 64 KB

    // bijective XCD chunk swizzle (m204); jt fast -> one gt's 3 n-blocks share an XCD
    const int nwg = gridDim.x;
    const int orig = blockIdx.x;
    const int q8 = nwg >> 3, r8 = nwg & 7, xc = orig & 7, oo = orig >> 3;
    const int wg = (xc < r8 ? xc * (q8 + 1) : r8 * (q8 + 1) + (xc - r8) * q8) + oo;
    const int gt = wg / 3, jt = wg % 3;

    const int v = tile_rel[gt];
    if (v < 0) return;  // uniform early-exit
    const bool comp = (v < N_REL);
    const int rel = comp ? v : N_REL;

    const int t = threadIdx.x;
    const int wid = t >> 6, lane = t & 63;
    const int wr = wid >> 2, wc = wid & 3;  // wave C block: rows [wr*128,+128) cols [wc*64,+64)
    const f16* Bp = WT + (size_t)rel * W_ELEMS + (size_t)(jt * 256) * DIM;

    // staging sources: half h, issue q: chunk c = q*512+t -> local row c>>3, swz k-chunk
    const f16* gA[2][2];
    const f16* gB[2][2];
#pragma unroll
    for (int h = 0; h < 2; ++h)
#pragma unroll
        for (int q = 0; q < 2; ++q) {
            const int c = q * 512 + t;
            const int r128 = c >> 3;
            const int gk = (c & 7) ^ (r128 & 7);
            const int row = h * 128 + r128;
            int arow;
            if (comp) {
                arow = srclist[gt * 256 + row];
            } else {
                arow = (v - N_REL) * 256 + row;
                if (arow > N_NODES - 1) arow = N_NODES - 1;
            }
            gA[h][q] = A + (size_t)arow * DIM + gk * 8;
            gB[h][q] = Bp + (size_t)row * DIM + gk * 8;
        }

#define STAGE(buf, ks)                                                                    \
    do {                                                                                  \
        _Pragma("unroll") for (int h = 0; h < 2; ++h) {                                   \
            _Pragma("unroll") for (int q = 0; q < 2; ++q) {                               \
                GLD(gA[h][q] + (ks) * BKS, (char*)As[buf][h] + q * 8192 + wid * 1024);    \
                GLD(gB[h][q] + (ks) * BKS, (char*)Bs[buf][h] + q * 8192 + wid * 1024);    \
            }                                                                             \
        }                                                                                 \
    } while (0)

    f32x4 acc[8][4];
#pragma unroll
    for (int i = 0; i < 8; ++i)
#pragma unroll
        for (int j = 0; j < 4; ++j) acc[i][j] = (f32x4){0.f, 0.f, 0.f, 0.f};

    const int lr16 = lane & 15, lk = lane >> 4, l7 = lane & 7;

    // prologue: stage K-step 0 into buf 0
    STAGE(0, 0);
    __syncthreads();

    for (int ks = 0; ks < NT; ++ks) {
        const int cur = ks & 1;
        if (ks < NT - 1) STAGE(cur ^ 1, ks + 1);  // issue next stage BEFORE compute
#pragma unroll
        for (int h = 0; h < 2; ++h) {
            const int cp = ((((h << 2) | lk) ^ l7)) * 8;  // swizzled k-chunk (f16 units)
            f16x8 b[4];
#pragma unroll
            for (int ni = 0; ni < 4; ++ni) {
                const int col = wc * 64 + ni * 16 + lr16;  // 0..255
                b[ni] = *(const f16x8*)&Bs[cur][col >> 7][(col & 127) * BKS + cp];
            }
#pragma unroll
            for (int mh = 0; mh < 2; ++mh) {
                f16x8 a[4];
#pragma unroll
                for (int m4 = 0; m4 < 4; ++m4) {
                    const int lrow = mh * 64 + m4 * 16 + lr16;  // 0..127 within half wr
                    a[m4] = *(const f16x8*)&As[cur][wr][lrow * BKS + cp];
                }
                __builtin_amdgcn_s_setprio(1);
#pragma unroll
                for (int m4 = 0; m4 < 4; ++m4)
#pragma unroll
                    for (int ni = 0; ni < 4; ++ni)
                        acc[mh * 4 + m4][ni] = __builtin_amdgcn_mfma_f32_16x16x32_f16(
                            a[m4], b[ni], acc[mh * 4 + m4][ni], 0, 0, 0);
                __builtin_amdgcn_s_setprio(0);
            }
        }
        __syncthreads();  // single barrier/K-step (drain lands after compute)
    }
#undef STAGE

    // epilogue: C/D layout col=lane&15, row=(lane>>4)*4+reg
    const int c0 = jt * 256 + wc * 64;
    if (comp) {
#pragma unroll
        for (int mi = 0; mi < 8; ++mi)
#pragma unroll
            for (int q = 0; q < 4; ++q) {
                const int z = gt * 256 + wr * 128 + mi * 16 + lk * 4 + q;  // padding rows ok
                f16* zp = Zout + (size_t)z * DIM + c0 + lr16;
#pragma unroll
                for (int ni = 0; ni < 4; ++ni) zp[ni * 16] = (f16)acc[mi][ni][q];
            }
    } else {
#pragma unroll
        for (int mi = 0; mi < 8; ++mi)
#pragma unroll
            for (int q = 0; q < 4; ++q) {
                const int row = (v - N_REL) * 256 + wr * 128 + mi * 16 + lk * 4 + q;
                if (row >= N_NODES) continue;
                float* op = aggout + (size_t)row * DIM + c0 + lr16;
#pragma unroll
                for (int ni = 0; ni < 4; ++ni) op[ni * 16] = acc[mi][ni][q];
            }
    }
}

// ---- fused gather + bias + LN + residual + relu ----
__device__ __forceinline__ float block_reduce3(float v, float* sm) {
#pragma unroll
    for (int o = 32; o > 0; o >>= 1) v += __shfl_down(v, o, 64);
    const int wid = threadIdx.x >> 6;
    const int lane = threadIdx.x & 63;
    __syncthreads();
    if (lane == 0) sm[wid] = v;
    __syncthreads();
    return sm[0] + sm[1] + sm[2];
}

__global__ void __launch_bounds__(192)
gather_ln_kernel(const f16* __restrict__ Z, const int* __restrict__ row_start,
                 const int* __restrict__ pack, const int* __restrict__ cnt,
                 const float* __restrict__ agg, const float* __restrict__ bias,
                 const float* __restrict__ g, const float* __restrict__ beta,
                 const f16* __restrict__ resid16, float* __restrict__ outf32,
                 f16* __restrict__ outf16, int do_relu) {
    __shared__ float sm[3];
    const int dst = blockIdx.x;
    const int t = threadIdx.x;
    const int lo = row_start[dst];
    const int hi = row_start[dst + 1];

    const float4 root = *reinterpret_cast<const float4*>(agg + (size_t)dst * DIM + t * 4);
    float a0 = root.x, a1 = root.y, a2 = root.z, a3 = root.w;
    for (int i = lo; i < hi; ++i) {
        const int p = pack[i];
        const int r = p >> 24;
        const int zrow = p & 0xFFFFFF;
        const float inv = 1.0f / (float)cnt[dst * N_REL + r];
        const f16x4 zv = *reinterpret_cast<const f16x4*>(Z + (size_t)zrow * DIM + t * 4);
        a0 += (float)zv[0] * inv;
        a1 += (float)zv[1] * inv;
        a2 += (float)zv[2] * inv;
        a3 += (float)zv[3] * inv;
    }
    const float4 b4 = *reinterpret_cast<const float4*>(bias + t * 4);
    a0 += b4.x; a1 += b4.y; a2 += b4.z; a3 += b4.w;

    const float mu = block_reduce3(a0 + a1 + a2 + a3, sm) * (1.0f / DIM);
    const float c0 = a0 - mu, c1 = a1 - mu, c2 = a2 - mu, c3 = a3 - mu;
    const float var = block_reduce3(c0 * c0 + c1 * c1 + c2 * c2 + c3 * c3, sm) * (1.0f / DIM);
    const float inv = rsqrtf(var + LN_EPS);

    const float4 g4 = *reinterpret_cast<const float4*>(g + t * 4);
    const float4 be4 = *reinterpret_cast<const float4*>(beta + t * 4);
    float o0 = c0 * inv * g4.x + be4.x;
    float o1 = c1 * inv * g4.y + be4.y;
    float o2 = c2 * inv * g4.z + be4.z;
    float o3 = c3 * inv * g4.w + be4.w;
    if (resid16 != nullptr) {
        const f16x4 rv = *reinterpret_cast<const f16x4*>(resid16 + (size_t)dst * DIM + t * 4);
        o0 += (float)rv[0]; o1 += (float)rv[1]; o2 += (float)rv[2]; o3 += (float)rv[3];
    }
    if (do_relu) {
        o0 = fmaxf(o0, 0.f); o1 = fmaxf(o1, 0.f); o2 = fmaxf(o2, 0.f); o3 = fmaxf(o3, 0.f);
    }
    if (outf32 != nullptr) {
        float4 ov = {o0, o1, o2, o3};
        *reinterpret_cast<float4*>(outf32 + (size_t)dst * DIM + t * 4) = ov;
    }
    if (outf16 != nullptr) {
        f16x4 hv = {(f16)o0, (f16)o1, (f16)o2, (f16)o3};
        *reinterpret_cast<f16x4*>(outf16 + (size_t)dst * DIM + t * 4) = hv;
    }
}

extern "C" void kernel_launch(void* const* d_in, const int* in_sizes, int n_in,
                              void* d_out, int out_size, void* d_ws, size_t ws_size,
                              hipStream_t stream) {
    const float* x      = (const float*)d_in[0];
    const int*   ei     = (const int*)d_in[1];
    const int*   et     = (const int*)d_in[2];
    const float* W_rel  = (const float*)d_in[3];
    const float* W_root = (const float*)d_in[4];
    const float* bias   = (const float*)d_in[5];
    const float* ln_g   = (const float*)d_in[6];
    const float* ln_b   = (const float*)d_in[7];
    float* out = (float*)d_out;

    // workspace carve-out
    char* w = (char*)d_ws;
    auto alloc = [&](size_t bytes) -> char* {
        char* p = w;
        w += (bytes + 255) & ~(size_t)255;
        return p;
    };
    f16* hf16      = (f16*)alloc((size_t)N_NODES * DIM * 2);
    f16* WT        = (f16*)alloc((size_t)(N_REL + 1) * W_ELEMS * 2);
    int* cnt       = (int*)alloc((size_t)N_NODES * N_REL * 4);
    int* deg       = (int*)alloc((size_t)N_NODES * 4);
    int* row_start = (int*)alloc((size_t)(N_NODES + 1) * 4);
    int* cursor    = (int*)alloc((size_t)N_NODES * 4);
    int* pack      = (int*)alloc((size_t)N_EDGES * 4);
    int* posmap    = (int*)alloc((size_t)N_REL * N_NODES * 4);
    int* mr        = (int*)alloc(64);
    int* zbase     = (int*)alloc(64);
    int* tile_rel  = (int*)alloc((size_t)GT2_ALL * 4);
    int* srclist   = (int*)alloc((size_t)GT2_MAX * 256 * 4);
    f16* Zg        = (f16*)w;  // remainder (~230 MB needed for compact Z, 256-padded)

    // ---- graph prep (layer-invariant, recomputed per call for determinism) ----
    hipMemsetAsync(cnt, 0, (size_t)N_NODES * N_REL * 4, stream);
    hipMemsetAsync(deg, 0, (size_t)N_NODES * 4, stream);
    hipMemsetAsync(posmap, 0xFF, (size_t)N_REL * N_NODES * 4, stream);  // -1
    hipMemsetAsync(tile_rel, 0xFF, (size_t)GT2_ALL * 4, stream);        // -1
    hipMemsetAsync(srclist, 0, (size_t)GT2_MAX * 256 * 4, stream);
    count_kernel<<<(N_EDGES + 255) / 256, 256, 0, stream>>>(ei, et, cnt, deg, posmap);
    posscan_kernel<<<N_REL, 256, 0, stream>>>(posmap, mr);
    scan_kernel<<<1, 256, 0, stream>>>(deg, row_start, cursor);
    zprep_kernel<<<1, 64, 0, stream>>>(mr, zbase, tile_rel);
    fill_kernel<<<(N_EDGES + 255) / 256, 256, 0, stream>>>(ei, et, posmap, zbase, cursor,
                                                           pack, srclist);
    convx_kernel<<<(N_NODES * DIM / 4 + 255) / 256, 256, 0, stream>>>(x, hf16);

    for (int l = 0; l < N_LAYERS; ++l) {
        convw_kernel<<<dim3(24, 24, N_REL + 1), dim3(32, 8), 0, stream>>>(W_rel, W_root, WT, l);

        // merged GEMM: compact Z tiles + dense root tiles (agg = d_out), 256^2 blocks
        gemm_kernel<<<GT2_ALL * 3, 512, 0, stream>>>(hf16, WT, srclist, tile_rel, Zg, out);

        // fused aggregate + bias + LN (+residual) (+relu)
        gather_ln_kernel<<<N_NODES, 192, 0, stream>>>(
            Zg, row_start, pack, cnt, out,
            bias + (size_t)l * DIM, ln_g + (size_t)l * DIM, ln_b + (size_t)l * DIM,
            (l > 0) ? hf16 : nullptr,
            (l == N_LAYERS - 1) ? out : nullptr,
            (l < N_LAYERS - 1) ? hf16 : nullptr,
            (l < N_LAYERS - 1) ? 1 : 0);
    }
}

// Round 15
// 1055.332 us; speedup vs baseline: 1.0292x; 1.0292x over previous
//
#include <hip/hip_runtime.h>

#define N_NODES 30000
#define N_EDGES 200000
#define DIM 768
#define N_REL 10
#define N_LAYERS 2
#define LN_EPS 1e-5f
#define W_ELEMS (DIM * DIM)
#define BKS 64              // GEMM k-step (r7/r12 proven config)
#define NT (DIM / BKS)      // 12 K-steps
#define GT_MAX 1573         // upper bound on compact row-tiles
#define N_ROOT_TILES ((N_NODES + 127) / 128)  // 235
#define GT_ALL (GT_MAX + N_ROOT_TILES)        // 1808
#define CONV_IDX (N_NODES * DIM / 4)          // convx work items

typedef _Float16 f16;
typedef _Float16 f16x4 __attribute__((ext_vector_type(4)));
typedef _Float16 f16x8 __attribute__((ext_vector_type(8)));
typedef float f32x4 __attribute__((ext_vector_type(4)));

#define GLD(gaddr, laddr)                                                              \
    __builtin_amdgcn_global_load_lds((const __attribute__((address_space(1))) void*)(gaddr), \
                                     (__attribute__((address_space(3))) void*)(laddr), 16, 0, 0)

// ---- fused: edge counting (cnt/deg/posmap mark) + x f32->f16 convert ----
__global__ void count_conv_kernel(const int* __restrict__ ei, const int* __restrict__ et,
                                  int* __restrict__ cnt, int* __restrict__ deg,
                                  int* __restrict__ posmap, const float* __restrict__ xin,
                                  f16* __restrict__ xout) {
    const int idx = blockIdx.x * blockDim.x + threadIdx.x;
    if (idx < N_EDGES) {
        const int src = ei[idx];
        const int dst = ei[N_EDGES + idx];
        const int r = et[idx];
        atomicAdd(&cnt[dst * N_REL + r], 1);
        atomicAdd(&deg[dst], 1);
        posmap[r * N_NODES + src] = 1;  // idempotent mark
    }
    if (idx < CONV_IDX) {
        const float4 v = *reinterpret_cast<const float4*>(xin + (size_t)idx * 4);
        f16x4 o = {(f16)v.x, (f16)v.y, (f16)v.z, (f16)v.w};
        *reinterpret_cast<f16x4*>(xout + (size_t)idx * 4) = o;
    }
}

// ---- per-relation position scan: flags -> dense positions (src-ordered), mr[r] ----
#define PSCAN_CHUNK 118  // 256*118 >= N_NODES
__global__ void posscan_kernel(int* __restrict__ posmap, int* __restrict__ mr) {
    __shared__ int part[256];
    const int r = blockIdx.x;
    int* pm = posmap + (size_t)r * N_NODES;
    const int t = threadIdx.x;
    const int c0 = t * PSCAN_CHUNK;
    int s = 0;
    for (int i = 0; i < PSCAN_CHUNK; ++i) {
        const int idx = c0 + i;
        if (idx < N_NODES && pm[idx] == 1) ++s;
    }
    part[t] = s;
    __syncthreads();
    if (t == 0) {
        int a = 0;
        for (int i = 0; i < 256; ++i) { const int v = part[i]; part[i] = a; a += v; }
        mr[r] = a;
    }
    __syncthreads();
    int a = part[t];
    for (int i = 0; i < PSCAN_CHUNK; ++i) {
        const int idx = c0 + i;
        if (idx < N_NODES && pm[idx] == 1) pm[idx] = a++;
    }
}

// ---- single-block: CSR row scan + (thread 0) zbase/tile_rel build ----
#define SCAN_CHUNK 118
__global__ void scan_zprep_kernel(const int* __restrict__ deg, const int* __restrict__ mr,
                                  int* __restrict__ row_start, int* __restrict__ cursor,
                                  int* __restrict__ zbase, int* __restrict__ tile_rel) {
    __shared__ int part[256];
    __shared__ int off[257];
    const int t = threadIdx.x;
    const int c0 = t * SCAN_CHUNK;
    int s = 0;
    for (int i = 0; i < SCAN_CHUNK; ++i) {
        const int idx = c0 + i;
        if (idx < N_NODES) s += deg[idx];
    }
    part[t] = s;
    __syncthreads();
    if (t == 0) {
        int a = 0;
        for (int i = 0; i < 256; ++i) { off[i] = a; a += part[i]; }
        off[256] = a;
        row_start[N_NODES] = a;
        // zprep tail: 128-aligned z-extents per relation + tile->rel table
        int zc = 0, tc = 0;
        for (int r = 0; r < N_REL; ++r) {
            zbase[r] = zc;
            const int nt = (mr[r] + 127) >> 7;
            for (int i = 0; i < nt; ++i) tile_rel[tc + i] = r;
            tc += nt;
            zc += nt << 7;
        }
        for (int i = 0; i < N_ROOT_TILES; ++i) tile_rel[tc + i] = N_REL + i;
    }
    __syncthreads();
    int a = off[t];
    for (int i = 0; i < SCAN_CHUNK; ++i) {
        const int idx = c0 + i;
        if (idx < N_NODES) {
            row_start[idx] = a;
            cursor[idx] = a;
            a += deg[idx];
        }
    }
}

// ---- fill CSR: pack = (rel<<24) | zrow; srclist[zrow] = src ----
__global__ void fill_kernel(const int* __restrict__ ei, const int* __restrict__ et,
                            const int* __restrict__ posmap, const int* __restrict__ zbase,
                            int* __restrict__ cursor, int* __restrict__ pack,
                            int* __restrict__ srclist) {
    int e = blockIdx.x * blockDim.x + threadIdx.x;
    if (e >= N_EDGES) return;
    int src = ei[e];
    int dst = ei[N_EDGES + e];
    int r = et[e];
    const int zrow = zbase[r] + posmap[r * N_NODES + src];
    int pos = atomicAdd(&cursor[dst], 1);
    pack[pos] = (r << 24) | zrow;
    srclist[zrow] = src;  // idempotent
}

// ---- W convert + transpose: WT[s][j][k] = Wsrc[s][k][j] as f16 ----
__global__ void convw_kernel(const float* __restrict__ Wrel, const float* __restrict__ Wroot,
                             f16* __restrict__ WT, int layer) {
    __shared__ float tile[32][33];
    const int s = blockIdx.z;
    const float* src = (s < N_REL) ? (Wrel + ((size_t)layer * N_REL + s) * W_ELEMS)
                                   : (Wroot + (size_t)layer * W_ELEMS);
    const int k0 = blockIdx.x * 32;
    const int j0 = blockIdx.y * 32;
    const int tx = threadIdx.x;
    const int ty = threadIdx.y;
#pragma unroll
    for (int i = 0; i < 4; ++i)
        tile[ty + i * 8][tx] = src[(size_t)(k0 + ty + i * 8) * DIM + j0 + tx];
    __syncthreads();
    f16* dst = WT + (size_t)s * W_ELEMS;
#pragma unroll
    for (int i = 0; i < 4; ++i)
        dst[(size_t)(j0 + ty + i * 8) * DIM + k0 + tx] = (f16)tile[tx][ty + i * 8];
}

// ---- f16 MFMA GEMM (proven 2-phase BK=64, 128^2/4-wave) — merged dispatch ----
// tile_rel[gt]: <0 exit | [0,N_REL) compact (A gathered via srclist, Z f16 out)
//             | >=N_REL root tile idx v-N_REL (dense rows, W_root slab, f32 agg out)
// LDS [128][64 f16] x2 bufs x2 ops = 64 KB -> 2 blocks/CU. 16B k-chunks
// XOR-swizzled c^(row&7): linear GLD dest + pre-swizzled src + swizzled read.
__global__ void __launch_bounds__(256)
gemm_kernel(const f16* __restrict__ A, const f16* __restrict__ WT,
            const int* __restrict__ srclist, const int* __restrict__ tile_rel,
            f16* __restrict__ Zout, float* __restrict__ aggout) {
    __shared__ alignas(128) f16 As[2][128 * BKS];  // 2 x 16 KB
    __shared__ alignas(128) f16 Bs[2][128 * BKS];  // 2 x 16 KB

    // bijective XCD chunk swizzle (m204)
    const int nwg = gridDim.x;
    const int orig = blockIdx.x;
    const int qq = nwg >> 3, rr = nwg & 7, xc = orig & 7, oo = orig >> 3;
    const int wg = (xc < rr ? xc * (qq + 1) : rr * (qq + 1) + (xc - rr) * qq) + oo;
    const int gt = wg / 6, jt = wg % 6;

    const int v = tile_rel[gt];
    if (v < 0) return;  // uniform early-exit
    const bool comp = (v < N_REL);
    const int rel = comp ? v : N_REL;

    const int t = threadIdx.x;
    const int wv = t >> 6, lane = t & 63;
    const int wr = wv >> 1, wc = wv & 1;
    const f16* B = WT + (size_t)rel * W_ELEMS + (size_t)(jt * 128) * DIM;

    // staging: 1024 16-B chunks per operand per K-step; issue q covers chunk q*256+t
    const f16* gA[4];
    const f16* gB[4];
#pragma unroll
    for (int q = 0; q < 4; ++q) {
        const int chunk = q * 256 + t;
        const int row = chunk >> 3;              // 0..127
        const int gk = (chunk & 7) ^ (row & 7);  // swizzled source chunk
        int arow;
        if (comp) {
            arow = srclist[gt * 128 + row];
        } else {
            arow = (v - N_REL) * 128 + row;
            if (arow > N_NODES - 1) arow = N_NODES - 1;
        }
        gA[q] = A + (size_t)arow * DIM + gk * 8;
        gB[q] = B + (size_t)row * DIM + gk * 8;
    }

    f32x4 acc[4][4];
#pragma unroll
    for (int i = 0; i < 4; ++i)
#pragma unroll
        for (int j = 0; j < 4; ++j) acc[i][j] = (f32x4){0.f, 0.f, 0.f, 0.f};

    const int lr16 = lane & 15, lk = lane >> 4, l7 = lane & 7;

    // prologue: stage K-step 0 into buf 0
#pragma unroll
    for (int q = 0; q < 4; ++q) {
        GLD(gA[q], (char*)As[0] + q * 4096 + wv * 1024);
        GLD(gB[q], (char*)Bs[0] + q * 4096 + wv * 1024);
    }
    __syncthreads();

    for (int ks = 0; ks < NT; ++ks) {
        const int cur = ks & 1;
        if (ks < NT - 1) {  // issue next tile's stage BEFORE compute
#pragma unroll
            for (int q = 0; q < 4; ++q) {
                GLD(gA[q] + (ks + 1) * BKS, (char*)As[cur ^ 1] + q * 4096 + wv * 1024);
                GLD(gB[q] + (ks + 1) * BKS, (char*)Bs[cur ^ 1] + q * 4096 + wv * 1024);
            }
        }
#pragma unroll
        for (int h = 0; h < 2; ++h) {
            f16x8 a[4], b[4];
            const int cp = (((h << 2) | lk) ^ l7) * 8;  // swizzled k-chunk (f16 units)
#pragma unroll
            for (int i = 0; i < 4; ++i) {
                a[i] = *(const f16x8*)&As[cur][(wr * 64 + i * 16 + lr16) * BKS + cp];
                b[i] = *(const f16x8*)&Bs[cur][(wc * 64 + i * 16 + lr16) * BKS + cp];
            }
#pragma unroll
            for (int mi = 0; mi < 4; ++mi)
#pragma unroll
                for (int ni = 0; ni < 4; ++ni)
                    acc[mi][ni] =
                        __builtin_amdgcn_mfma_f32_16x16x32_f16(a[mi], b[ni], acc[mi][ni], 0, 0, 0);
        }
        __syncthreads();  // single barrier/K-step (drain lands after compute)
    }

    const int lrow = lk * 4, lcol = lr16;
    const int c0 = jt * 128 + wc * 64;
    if (comp) {
#pragma unroll
        for (int mi = 0; mi < 4; ++mi)
#pragma unroll
            for (int q = 0; q < 4; ++q) {
                const int z = gt * 128 + wr * 64 + mi * 16 + lrow + q;  // padding rows ok
                f16* zp = Zout + (size_t)z * DIM + c0 + lcol;
#pragma unroll
                for (int ni = 0; ni < 4; ++ni) zp[ni * 16] = (f16)acc[mi][ni][q];
            }
    } else {
#pragma unroll
        for (int mi = 0; mi < 4; ++mi)
#pragma unroll
            for (int q = 0; q < 4; ++q) {
                const int row = (v - N_REL) * 128 + wr * 64 + mi * 16 + lrow + q;
                if (row >= N_NODES) continue;
                float* op = aggout + (size_t)row * DIM + c0 + lcol;
#pragma unroll
                for (int ni = 0; ni < 4; ++ni) op[ni * 16] = acc[mi][ni][q];
            }
    }
}

// ---- fused gather + bias + LN + residual + relu ----
__device__ __forceinline__ float block_reduce3(float v, float* sm) {
#pragma unroll
    for (int o = 32; o > 0; o >>= 1) v += __shfl_down(v, o, 64);
    const int wid = threadIdx.x >> 6;
    const int lane = threadIdx.x & 63;
    __syncthreads();
    if (lane == 0) sm[wid] = v;
    __syncthreads();
    return sm[0] + sm[1] + sm[2];
}

__global__ void __launch_bounds__(192)
gather_ln_kernel(const f16* __restrict__ Z, const int* __restrict__ row_start,
                 const int* __restrict__ pack, const int* __restrict__ cnt,
                 const float* __restrict__ agg, const float* __restrict__ bias,
                 const float* __restrict__ g, const float* __restrict__ beta,
                 const f16* __restrict__ resid16, float* __restrict__ outf32,
                 f16* __restrict__ outf16, int do_relu) {
    __shared__ float sm[3];
    const int dst = blockIdx.x;
    const int t = threadIdx.x;
    const int lo = row_start[dst];
    const int hi = row_start[dst + 1];

    const float4 root = *reinterpret_cast<const float4*>(agg + (size_t)dst * DIM + t * 4);
    float a0 = root.x, a1 = root.y, a2 = root.z, a3 = root.w;
    for (int i = lo; i < hi; ++i) {
        const int p = pack[i];
        const int r = p >> 24;
        const int zrow = p & 0xFFFFFF;
        const float inv = 1.0f / (float)cnt[dst * N_REL + r];
        const f16x4 zv = *reinterpret_cast<const f16x4*>(Z + (size_t)zrow * DIM + t * 4);
        a0 += (float)zv[0] * inv;
        a1 += (float)zv[1] * inv;
        a2 += (float)zv[2] * inv;
        a3 += (float)zv[3] * inv;
    }
    const float4 b4 = *reinterpret_cast<const float4*>(bias + t * 4);
    a0 += b4.x; a1 += b4.y; a2 += b4.z; a3 += b4.w;

    const float mu = block_reduce3(a0 + a1 + a2 + a3, sm) * (1.0f / DIM);
    const float c0 = a0 - mu, c1 = a1 - mu, c2 = a2 - mu, c3 = a3 - mu;
    const float var = block_reduce3(c0 * c0 + c1 * c1 + c2 * c2 + c3 * c3, sm) * (1.0f / DIM);
    const float inv = rsqrtf(var + LN_EPS);

    const float4 g4 = *reinterpret_cast<const float4*>(g + t * 4);
    const float4 be4 = *reinterpret_cast<const float4*>(beta + t * 4);
    float o0 = c0 * inv * g4.x + be4.x;
    float o1 = c1 * inv * g4.y + be4.y;
    float o2 = c2 * inv * g4.z + be4.z;
    float o3 = c3 * inv * g4.w + be4.w;
    if (resid16 != nullptr) {
        const f16x4 rv = *reinterpret_cast<const f16x4*>(resid16 + (size_t)dst * DIM + t * 4);
        o0 += (float)rv[0]; o1 += (float)rv[1]; o2 += (float)rv[2]; o3 += (float)rv[3];
    }
    if (do_relu) {
        o0 = fmaxf(o0, 0.f); o1 = fmaxf(o1, 0.f); o2 = fmaxf(o2, 0.f); o3 = fmaxf(o3, 0.f);
    }
    if (outf32 != nullptr) {
        float4 ov = {o0, o1, o2, o3};
        *reinterpret_cast<float4*>(outf32 + (size_t)dst * DIM + t * 4) = ov;
    }
    if (outf16 != nullptr) {
        f16x4 hv = {(f16)o0, (f16)o1, (f16)o2, (f16)o3};
        *reinterpret_cast<f16x4*>(outf16 + (size_t)dst * DIM + t * 4) = hv;
    }
}

extern "C" void kernel_launch(void* const* d_in, const int* in_sizes, int n_in,
                              void* d_out, int out_size, void* d_ws, size_t ws_size,
                              hipStream_t stream) {
    const float* x      = (const float*)d_in[0];
    const int*   ei     = (const int*)d_in[1];
    const int*   et     = (const int*)d_in[2];
    const float* W_rel  = (const float*)d_in[3];
    const float* W_root = (const float*)d_in[4];
    const float* bias   = (const float*)d_in[5];
    const float* ln_g   = (const float*)d_in[6];
    const float* ln_b   = (const float*)d_in[7];
    float* out = (float*)d_out;

    // workspace carve-out — ordered so memsets coalesce:
    //   [cnt|deg|srclist] -> one memset(0); [posmap|tile_rel] -> one memset(0xFF)
    char* w = (char*)d_ws;
    auto alloc = [&](size_t bytes) -> char* {
        char* p = w;
        w += (bytes + 255) & ~(size_t)255;
        return p;
    };
    f16* hf16      = (f16*)alloc((size_t)N_NODES * DIM * 2);
    f16* WT        = (f16*)alloc((size_t)(N_REL + 1) * W_ELEMS * 2);
    char* z0       = w;  // zero-group start
    int* cnt       = (int*)alloc((size_t)N_NODES * N_REL * 4);
    int* deg       = (int*)alloc((size_t)N_NODES * 4);
    int* srclist   = (int*)alloc((size_t)GT_MAX * 128 * 4);
    const size_t z_bytes = (size_t)(w - z0);
    char* f0       = w;  // 0xFF-group start
    int* posmap    = (int*)alloc((size_t)N_REL * N_NODES * 4);
    int* tile_rel  = (int*)alloc((size_t)GT_ALL * 4);
    const size_t f_bytes = (size_t)(w - f0);
    int* row_start = (int*)alloc((size_t)(N_NODES + 1) * 4);
    int* cursor    = (int*)alloc((size_t)N_NODES * 4);
    int* pack      = (int*)alloc((size_t)N_EDGES * 4);
    int* mr        = (int*)alloc(64);
    int* zbase     = (int*)alloc(64);
    f16* Zg        = (f16*)w;  // remainder (~226 MB touched for compact Z)

    // ---- graph prep (layer-invariant, recomputed per call for determinism) ----
    hipMemsetAsync(z0, 0, z_bytes, stream);
    hipMemsetAsync(f0, 0xFF, f_bytes, stream);
    count_conv_kernel<<<(CONV_IDX + 255) / 256, 256, 0, stream>>>(ei, et, cnt, deg, posmap,
                                                                  x, hf16);
    posscan_kernel<<<N_REL, 256, 0, stream>>>(posmap, mr);
    scan_zprep_kernel<<<1, 256, 0, stream>>>(deg, mr, row_start, cursor, zbase, tile_rel);
    fill_kernel<<<(N_EDGES + 255) / 256, 256, 0, stream>>>(ei, et, posmap, zbase, cursor,
                                                           pack, srclist);

    for (int l = 0; l < N_LAYERS; ++l) {
        convw_kernel<<<dim3(24, 24, N_REL + 1), dim3(32, 8), 0, stream>>>(W_rel, W_root, WT, l);

        // merged GEMM: compact Z tiles + dense root tiles (agg = d_out) in one dispatch
        gemm_kernel<<<GT_ALL * 6, 256, 0, stream>>>(hf16, WT, srclist, tile_rel, Zg, out);

        // fused aggregate + bias + LN (+residual) (+relu)
        gather_ln_kernel<<<N_NODES, 192, 0, stream>>>(
            Zg, row_start, pack, cnt, out,
            bias + (size_t)l * DIM, ln_g + (size_t)l * DIM, ln_b + (size_t)l * DIM,
            (l > 0) ? hf16 : nullptr,
            (l == N_LAYERS - 1) ? out : nullptr,
            (l < N_LAYERS - 1) ? hf16 : nullptr,
            (l < N_LAYERS - 1) ? 1 : 0);
    }
}